// Round 11
// baseline (560.049 us; speedup 1.0000x reference)
//
#include <hip/hip_runtime.h>
#include <math.h>

#define NN 50000
#define EE 800000
#define EEN (EE+NN)          // edges + self loops
#define STRIDE 64            // fixed CSR stride: self + up to 63 in-edges
#define NFEAT 4
#define EFEAT 4
#define EMBD 16
#define IN0 20   // NF + EMB
#define HIDD 64
#define OUTD 128

// bf16 helpers: storage = unsigned short, RTN-even pack, shift-decode
__device__ __forceinline__ unsigned short f2bf(float f){
  unsigned u = __float_as_uint(f);
  return (unsigned short)((u + 0x7FFFu + ((u>>16)&1u)) >> 16);
}
__device__ __forceinline__ float bfl(unsigned u){ return __uint_as_float(u<<16); }
__device__ __forceinline__ float bfh(unsigned u){ return __uint_as_float(u & 0xFFFF0000u); }

template<int V> struct ldt;
template<> struct ldt<4>{ using T = uint2; };
template<> struct ldt<2>{ using T = unsigned int; };

// ---------------- fixed-stride CSR scatter (one kernel, no scan) ----------
// col[n*64] = n (self); col[n*64+1+k] = src. epos[e] = CSR slot of edge e so
// k_edge writes alpha IN CSR ORDER (k_agg streams it — R6/R10-proven; random
// pp reads in k_agg cost +47MB FETCH, measured R7/R9).
__global__ void k_scatter(const int* __restrict__ ei, int* fill,
                          int* __restrict__ col, int* __restrict__ epos){
  int idx = blockIdx.x*blockDim.x + threadIdx.x;
  if (idx < EE){
    int d = ei[EE+idx];
    int pos = atomicAdd(&fill[d],1);
    col[d*STRIDE + 1 + pos] = ei[idx];
    epos[idx] = d*STRIDE + 1 + pos;
  } else if (idx < EEN){
    int n = idx-EE;
    col[n*STRIDE] = n;
  }
}

// ---------------- av (3 layers) + zred init + fill zero, one launch --------
template<int F_IN,int HH,int CC>
__device__ __forceinline__ void av_one(const float* W, const float* asrc,
                                       const float* adst, float* av, int tid){
  if (tid >= HH*F_IN) return;
  int h = tid / F_IN, f = tid % F_IN;
  float s1=0.f, s2=0.f;
  for (int c=0;c<CC;c++){
    float wv = W[(size_t)(h*CC+c)*F_IN+f];
    s1 += asrc[h*CC+c]*wv;
    s2 += adst[h*CC+c]*wv;
  }
  av[tid] = s1;
  av[HH*F_IN+tid] = s2;
}
__global__ void k_av3(const float* W0, const float* as0, const float* ad0, float* av0,
                      const float* W1, const float* as1, const float* ad1, float* av1,
                      const float* W2, const float* as2, const float* ad2, float* av2,
                      int* fill, float* zred){
  int tid = threadIdx.x;
  int gi = blockIdx.x*256 + tid;
  if (gi < NN) fill[gi] = 0;
  if      (blockIdx.x==0){ av_one<IN0,4,64> (W0, as0, ad0, av0, tid); if (tid<24) zred[tid]=0.f; }
  else if (blockIdx.x==1) av_one<64,4,64>  (W1, as1, ad1, av1, tid);
  else if (blockIdx.x==2) av_one<64,1,128> (W2, as2, ad2, av2, tid);
}

// ---------------- outer-product register-tiled GEMM + fused scores --------
template<int K,int NCOL,int HH,bool CONCAT>
__global__ __launch_bounds__(256)
void k_gemm(const float* __restrict__ xin, const int* __restrict__ jt,
            const float* __restrict__ emb, const float* __restrict__ W,
            const float* __restrict__ avp, unsigned short* __restrict__ hout,
            float* __restrict__ si, float* __restrict__ sj){
  constexpr int PITCH = 132;
  __shared__ float xT[K*PITCH];
  __shared__ float wT[K*PITCH];
  __shared__ float EMBL[CONCAT ? 17*EMBD : 1];
  int tid = threadIdx.x;
  int rbase = blockIdx.x*128, cbase = blockIdx.y*128;
  if (CONCAT){
    for (int i=tid; i<17*EMBD; i+=256) EMBL[i]=emb[i];
    __syncthreads();
    if (tid < 128){
      int row = tid;
      int gr = rbase+row; if (gr >= NN) gr = NN-1;
      float4 v = ((const float4*)xin)[gr];
      xT[0*PITCH+row]=v.x; xT[1*PITCH+row]=v.y;
      xT[2*PITCH+row]=v.z; xT[3*PITCH+row]=v.w;
      int j = jt[gr];
      #pragma unroll
      for (int k=0;k<EMBD;k++) xT[(NFEAT+k)*PITCH+row] = EMBL[j*EMBD+k];
    } else {
      int col = tid-128;
      const float4* wp = (const float4*)(W + (size_t)(cbase+col)*K);
      #pragma unroll
      for (int k4=0;k4<K/4;k4++){
        float4 v = wp[k4];
        wT[(4*k4+0)*PITCH+col]=v.x; wT[(4*k4+1)*PITCH+col]=v.y;
        wT[(4*k4+2)*PITCH+col]=v.z; wT[(4*k4+3)*PITCH+col]=v.w;
      }
    }
  } else {
    constexpr int K4 = K/4;
    for (int i=tid; i<128*K4; i+=256){
      int row = i/K4, k4 = i%K4;
      int gr = rbase+row; if (gr >= NN) gr = NN-1;
      float4 v = ((const float4*)xin)[(size_t)gr*K4 + k4];
      xT[(4*k4+0)*PITCH+row]=v.x; xT[(4*k4+1)*PITCH+row]=v.y;
      xT[(4*k4+2)*PITCH+row]=v.z; xT[(4*k4+3)*PITCH+row]=v.w;
    }
    for (int i=tid; i<128*K4; i+=256){
      int col = i/K4, k4 = i%K4;
      float4 v = ((const float4*)W)[(size_t)(cbase+col)*K4 + k4];
      wT[(4*k4+0)*PITCH+col]=v.x; wT[(4*k4+1)*PITCH+col]=v.y;
      wT[(4*k4+2)*PITCH+col]=v.z; wT[(4*k4+3)*PITCH+col]=v.w;
    }
  }
  __syncthreads();
  int lane = tid & 63, w = tid >> 6;
  int r0 = (w>>1)*64 + (lane&7)*8;
  int c0 = (w&1)*64 + (lane>>3)*8;
  float acc[8][8];
  #pragma unroll
  for (int i=0;i<8;i++)
    #pragma unroll
    for (int j=0;j<8;j++) acc[i][j]=0.f;
  #pragma unroll 4
  for (int k=0;k<K;k++){
    float a[8], b[8];
    *(float4*)&a[0] = *(const float4*)&xT[k*PITCH + r0];
    *(float4*)&a[4] = *(const float4*)&xT[k*PITCH + r0 + 4];
    *(float4*)&b[0] = *(const float4*)&wT[k*PITCH + c0];
    *(float4*)&b[4] = *(const float4*)&wT[k*PITCH + c0 + 4];
    #pragma unroll
    for (int i=0;i<8;i++)
      #pragma unroll
      for (int j=0;j<8;j++) acc[i][j] += a[i]*b[j];
  }
  if (blockIdx.y==0 && tid < 128){
    int row = tid, gr = rbase+row;
    if (gr < NN){
      #pragma unroll
      for (int h=0;h<HH;h++){
        float a=0.f, b=0.f;
        for (int k=0;k<K;k++){
          float xv = xT[k*PITCH+row];
          a += xv*avp[h*K+k];
          b += xv*avp[HH*K+h*K+k];
        }
        si[(size_t)gr*HH+h]=a;
        sj[(size_t)gr*HH+h]=b;
      }
    }
  }
  #pragma unroll
  for (int i=0;i<8;i++){
    int n = rbase + r0 + i;
    if (n < NN){
      uint4 o;
      o.x = (unsigned)f2bf(acc[i][0]) | ((unsigned)f2bf(acc[i][1])<<16);
      o.y = (unsigned)f2bf(acc[i][2]) | ((unsigned)f2bf(acc[i][3])<<16);
      o.z = (unsigned)f2bf(acc[i][4]) | ((unsigned)f2bf(acc[i][5])<<16);
      o.w = (unsigned)f2bf(acc[i][6]) | ((unsigned)f2bf(acc[i][7])<<16);
      *(uint4*)(hout + (size_t)n*NCOL + cbase + c0) = o;
    }
  }
}

// ---------------- per-edge exp(lrelu(score)) + global per-head sum ----------
template<int HH>
__global__ void k_edge(const int* __restrict__ ei, const float* __restrict__ eattr,
                       const float* __restrict__ We, const float* __restrict__ si,
                       const float* __restrict__ sj, const int* __restrict__ epos,
                       float* __restrict__ pp, float* __restrict__ zred){
  int idx = blockIdx.x*blockDim.x + threadIdx.x;
  float z[HH];
  #pragma unroll
  for (int h=0;h<HH;h++) z[h]=0.f;
  if (idx < EE){
    int s = ei[idx], d = ei[EE+idx];
    const float4 ea = ((const float4*)eattr)[idx];
    int pos = epos[idx];
    if (HH==4){
      float4 siv = ((const float4*)si)[d];
      float4 sjv = ((const float4*)sj)[s];
      float te[4] = {siv.x+sjv.x, siv.y+sjv.y, siv.z+sjv.z, siv.w+sjv.w};
      float pv[4];
      #pragma unroll
      for (int h=0;h<4;h++){
        float t = te[h] + ea.x*We[h*EFEAT+0] + ea.y*We[h*EFEAT+1]
                        + ea.z*We[h*EFEAT+2] + ea.w*We[h*EFEAT+3];
        t = (t>0.f)? t : 0.2f*t;
        float p = expf(t);
        z[h]=p; pv[h]=p;
      }
      ((float4*)pp)[pos] = make_float4(pv[0],pv[1],pv[2],pv[3]);
    } else {
      float t = si[d] + sj[s]
              + ea.x*We[0] + ea.y*We[1] + ea.z*We[2] + ea.w*We[3];
      t = (t>0.f)? t : 0.2f*t;
      float p = expf(t);
      z[0]=p;
      pp[pos] = p;
    }
  } else if (idx < EEN){
    int n = idx-EE;
    int pos = n*STRIDE;
    if (HH==4){
      float4 siv = ((const float4*)si)[n];
      float4 sjv = ((const float4*)sj)[n];
      float te[4] = {siv.x+sjv.x, siv.y+sjv.y, siv.z+sjv.z, siv.w+sjv.w};
      float pv[4];
      #pragma unroll
      for (int h=0;h<4;h++){
        float t = te[h];
        t = (t>0.f)? t : 0.2f*t;
        float p = expf(t);
        z[h]=p; pv[h]=p;
      }
      ((float4*)pp)[pos] = make_float4(pv[0],pv[1],pv[2],pv[3]);
    } else {
      float t = si[n]+sj[n];
      t = (t>0.f)? t : 0.2f*t;
      float p = expf(t);
      z[0]=p;
      pp[pos]=p;
    }
  }
  __shared__ float zs[4][HH];
  #pragma unroll
  for (int h=0;h<HH;h++){
    float v=z[h];
    #pragma unroll
    for (int off=32; off>0; off>>=1) v += __shfl_xor(v,off,64);
    if ((threadIdx.x&63)==0) zs[threadIdx.x>>6][h]=v;
  }
  __syncthreads();
  if (threadIdx.x < HH){
    float tot = zs[0][threadIdx.x]+zs[1][threadIdx.x]
              + zs[2][threadIdx.x]+zs[3][threadIdx.x];
    atomicAdd(&zred[threadIdx.x], tot);
  }
}

// ---------------- pull aggregation: 2 waves per node, bf16 gather ----------
// Block = 512 thr = 8 waves = 4 nodes x 2 waves. Each wave walks half of its
// node's CSR segment (4-unroll + remainder); partials combined via LDS, first
// wave finalizes. Memory pattern identical to R10 (col+pp stream once, h
// random-gathers) — only concurrency doubles and the serial tail halves.
template<int HH,int CC,bool DO_ELU>
__global__ __launch_bounds__(512)
void k_agg(const unsigned short* __restrict__ hb, const float* __restrict__ pp,
           const float* __restrict__ zred, const int* __restrict__ fill,
           const int* __restrict__ col, float* __restrict__ outp){
  constexpr int HC = HH*CC;
  constexpr int V  = HC/64;
  using LT = typename ldt<V>::T;
  __shared__ float sm[8*64*V];
  int tid = threadIdx.x;
  int w = tid>>6, lane = tid&63;
  int n = blockIdx.x*4 + (w>>1);         // NN % 4 == 0
  int half = w&1;
  int hd = (lane*V)/CC;
  float acc[V];
  #pragma unroll
  for (int v=0;v<V;v++) acc[v]=0.f;
  auto mac = [&](float p, LT h){
    if constexpr (V==4){
      acc[0] += p*bfl(h.x); acc[1] += p*bfh(h.x);
      acc[2] += p*bfl(h.y); acc[3] += p*bfh(h.y);
    } else {
      acc[0] += p*bfl(h);   acc[1] += p*bfh(h);
    }
  };
  int beg = n*STRIDE;
  int cnt = 1 + fill[n];
  int cA  = (cnt+1)>>1;
  int i   = beg + (half ? cA : 0);
  int end = beg + (half ? cnt : cA);
  for (; i+4<=end; i+=4){
    int sr[4]; float p[4]; LT h[4];
    #pragma unroll
    for (int k=0;k<4;k++) sr[k]=col[i+k];
    #pragma unroll
    for (int k=0;k<4;k++)
      p[k] = (HH==4) ? pp[(size_t)(i+k)*4+hd] : pp[i+k];
    #pragma unroll
    for (int k=0;k<4;k++) h[k]=((const LT*)(hb + (size_t)sr[k]*HC))[lane];
    #pragma unroll
    for (int k=0;k<4;k++) mac(p[k], h[k]);
  }
  for (; i<end; i++){
    int sr = col[i];
    float p = (HH==4) ? pp[(size_t)i*4+hd] : pp[i];
    LT h = ((const LT*)(hb + (size_t)sr*HC))[lane];
    mac(p, h);
  }
  #pragma unroll
  for (int v=0;v<V;v++) sm[(w*64+lane)*V+v] = acc[v];
  __syncthreads();
  if (half==0){
    #pragma unroll
    for (int v=0;v<V;v++) acc[v] += sm[((w+1)*64+lane)*V+v];
    float invZ = 1.0f/zred[hd];
    #pragma unroll
    for (int v=0;v<V;v++) acc[v] *= invZ;
    if (HH==4){
      #pragma unroll
      for (int off=16; off<64; off<<=1){
        #pragma unroll
        for (int v=0;v<V;v++) acc[v] += __shfl_xor(acc[v], off, 64);
      }
      if (lane < 16){
        float4 o;
        o.x=0.25f*acc[0]; o.y=0.25f*acc[1]; o.z=0.25f*acc[2]; o.w=0.25f*acc[3];
        if (DO_ELU){
          o.x = (o.x>0.f)? o.x : expm1f(o.x);
          o.y = (o.y>0.f)? o.y : expm1f(o.y);
          o.z = (o.z>0.f)? o.z : expm1f(o.z);
          o.w = (o.w>0.f)? o.w : expm1f(o.w);
        }
        ((float4*)outp)[(size_t)n*(CC/4)+lane] = o;
      }
    } else {
      float2 o; o.x=acc[0]; o.y=acc[1];
      if (DO_ELU){
        o.x = (o.x>0.f)? o.x : expm1f(o.x);
        o.y = (o.y>0.f)? o.y : expm1f(o.y);
      }
      ((float2*)outp)[(size_t)n*(CC/2)+lane] = o;
    }
  }
}

extern "C" void kernel_launch(void* const* d_in, const int* in_sizes, int n_in,
                              void* d_out, int out_size, void* d_ws, size_t ws_size,
                              hipStream_t stream){
  const float* x    = (const float*)d_in[0];
  const int*   ei   = (const int*)d_in[1];
  const float* eatt = (const float*)d_in[2];
  const int*   jt   = (const int*)d_in[3];
  const float* emb  = (const float*)d_in[4];
  const float* W0   = (const float*)d_in[5];
  const float* as0  = (const float*)d_in[6];
  const float* ad0  = (const float*)d_in[7];
  const float* We0  = (const float*)d_in[8];
  const float* W1   = (const float*)d_in[9];
  const float* as1  = (const float*)d_in[10];
  const float* ad1  = (const float*)d_in[11];
  const float* We1  = (const float*)d_in[12];
  const float* W2   = (const float*)d_in[13];
  const float* as2  = (const float*)d_in[14];
  const float* ad2  = (const float*)d_in[15];
  const float* We2  = (const float*)d_in[16];
  float* out = (float*)d_out;

  char* p = (char*)d_ws;
  auto alloc = [&](size_t bytes)->char*{
    char* r = p; p += (bytes + 255) & ~(size_t)255; return r;
  };
  unsigned short* hbuf = (unsigned short*)alloc((size_t)NN*256*2); // 25.6 MB bf16
  float* x1     = (float*)alloc((size_t)NN*64*4);
  float* x2     = (float*)alloc((size_t)NN*64*4);
  float* si     = (float*)alloc((size_t)NN*4*4);
  float* sj     = (float*)alloc((size_t)NN*4*4);
  float* pp     = (float*)alloc((size_t)NN*STRIDE*16); // 51.2 MB CSR-slot alphas
  int*   fill   = (int*)alloc((size_t)NN*4);
  int*   col    = (int*)alloc((size_t)NN*STRIDE*4);    // 12.8 MB fixed-stride CSR
  int*   epos   = (int*)alloc((size_t)EE*4);
  float* av0    = (float*)alloc(512*4);
  float* av1    = (float*)alloc(512*4);
  float* av2    = (float*)alloc(512*4);
  float* zred   = (float*)alloc(3*8*4);

  k_av3    <<<dim3((NN+255)/256),  256, 0, stream>>>(W0,as0,ad0,av0, W1,as1,ad1,av1,
                                                     W2,as2,ad2,av2, fill, zred);
  k_scatter<<<dim3((EEN+255)/256), 256, 0, stream>>>(ei, fill, col, epos);

  dim3 gg01((NN+127)/128, 2);
  dim3 gg2 ((NN+127)/128, 1);
  dim3 egrid((EEN+255)/256);
  dim3 agrid(NN/4);

  // layer 0: concat(x, emb[jt]) -> [N,4,64]
  k_gemm<IN0,256,4,true> <<<gg01, 256, 0, stream>>>(x, jt, emb, W0, av0, hbuf, si, sj);
  k_edge<4>              <<<egrid,256, 0, stream>>>(ei, eatt, We0, si, sj, epos, pp, zred+0);
  k_agg<4,64,true>       <<<agrid,512, 0, stream>>>(hbuf, pp, zred+0, fill, col, x1);

  // layer 1: 64 -> [N,4,64]
  k_gemm<64,256,4,false> <<<gg01, 256, 0, stream>>>(x1, jt, emb, W1, av1, hbuf, si, sj);
  k_edge<4>              <<<egrid,256, 0, stream>>>(ei, eatt, We1, si, sj, epos, pp, zred+8);
  k_agg<4,64,true>       <<<agrid,512, 0, stream>>>(hbuf, pp, zred+8, fill, col, x2);

  // layer 2: 64 -> [N,1,128], no ELU on final output
  k_gemm<64,128,1,false> <<<gg2,  256, 0, stream>>>(x2, jt, emb, W2, av2, hbuf, si, sj);
  k_edge<1>              <<<egrid,256, 0, stream>>>(ei, eatt, We2, si, sj, epos, pp, zred+16);
  k_agg<1,128,false>     <<<agrid,512, 0, stream>>>(hbuf, pp, zred+16, fill, col, out);
}

// Round 12
// 556.095 us; speedup vs baseline: 1.0071x; 1.0071x over previous
//
#include <hip/hip_runtime.h>
#include <math.h>

#define NN 50000
#define EE 800000
#define EEN (EE+NN)          // edges + self loops
#define STRIDE 64            // fixed CSR stride: self + up to 63 in-edges
#define NFEAT 4
#define EFEAT 4
#define EMBD 16
#define IN0 20   // NF + EMB
#define HIDD 64
#define OUTD 128

// bf16 helpers: storage = unsigned short, RTN-even pack, shift-decode
__device__ __forceinline__ unsigned short f2bf(float f){
  unsigned u = __float_as_uint(f);
  return (unsigned short)((u + 0x7FFFu + ((u>>16)&1u)) >> 16);
}
__device__ __forceinline__ float bfl(unsigned u){ return __uint_as_float(u<<16); }
__device__ __forceinline__ float bfh(unsigned u){ return __uint_as_float(u & 0xFFFF0000u); }

template<int V> struct ldt;
template<> struct ldt<4>{ using T = uint2; };
template<> struct ldt<2>{ using T = unsigned int; };

// ---------------- fixed-stride CSR scatter (one kernel, no scan) ----------
// col[n*64] = n (self); col[n*64+1+k] = src. epos[e] = CSR slot of edge e so
// k_edge writes alpha IN CSR ORDER (k_agg streams it — R6/R10-proven; random
// pp reads in k_agg cost +47MB FETCH, measured R7/R9).
__global__ void k_scatter(const int* __restrict__ ei, int* fill,
                          int* __restrict__ col, int* __restrict__ epos){
  int idx = blockIdx.x*blockDim.x + threadIdx.x;
  if (idx < EE){
    int d = ei[EE+idx];
    int pos = atomicAdd(&fill[d],1);
    col[d*STRIDE + 1 + pos] = ei[idx];
    epos[idx] = d*STRIDE + 1 + pos;
  } else if (idx < EEN){
    int n = idx-EE;
    col[n*STRIDE] = n;
  }
}

// ---------------- av (3 layers) + zred init + fill zero, one launch --------
template<int F_IN,int HH,int CC>
__device__ __forceinline__ void av_one(const float* W, const float* asrc,
                                       const float* adst, float* av, int tid){
  if (tid >= HH*F_IN) return;
  int h = tid / F_IN, f = tid % F_IN;
  float s1=0.f, s2=0.f;
  for (int c=0;c<CC;c++){
    float wv = W[(size_t)(h*CC+c)*F_IN+f];
    s1 += asrc[h*CC+c]*wv;
    s2 += adst[h*CC+c]*wv;
  }
  av[tid] = s1;
  av[HH*F_IN+tid] = s2;
}
__global__ void k_av3(const float* W0, const float* as0, const float* ad0, float* av0,
                      const float* W1, const float* as1, const float* ad1, float* av1,
                      const float* W2, const float* as2, const float* ad2, float* av2,
                      int* fill, float* zred){
  int tid = threadIdx.x;
  int gi = blockIdx.x*256 + tid;
  if (gi < NN) fill[gi] = 0;
  if      (blockIdx.x==0){ av_one<IN0,4,64> (W0, as0, ad0, av0, tid); if (tid<24) zred[tid]=0.f; }
  else if (blockIdx.x==1) av_one<64,4,64>  (W1, as1, ad1, av1, tid);
  else if (blockIdx.x==2) av_one<64,1,128> (W2, as2, ad2, av2, tid);
}

// ---------------- outer-product register-tiled GEMM + fused scores --------
template<int K,int NCOL,int HH,bool CONCAT>
__global__ __launch_bounds__(256)
void k_gemm(const float* __restrict__ xin, const int* __restrict__ jt,
            const float* __restrict__ emb, const float* __restrict__ W,
            const float* __restrict__ avp, unsigned short* __restrict__ hout,
            float* __restrict__ si, float* __restrict__ sj){
  constexpr int PITCH = 132;
  __shared__ float xT[K*PITCH];
  __shared__ float wT[K*PITCH];
  __shared__ float EMBL[CONCAT ? 17*EMBD : 1];
  int tid = threadIdx.x;
  int rbase = blockIdx.x*128, cbase = blockIdx.y*128;
  if (CONCAT){
    for (int i=tid; i<17*EMBD; i+=256) EMBL[i]=emb[i];
    __syncthreads();
    if (tid < 128){
      int row = tid;
      int gr = rbase+row; if (gr >= NN) gr = NN-1;
      float4 v = ((const float4*)xin)[gr];
      xT[0*PITCH+row]=v.x; xT[1*PITCH+row]=v.y;
      xT[2*PITCH+row]=v.z; xT[3*PITCH+row]=v.w;
      int j = jt[gr];
      #pragma unroll
      for (int k=0;k<EMBD;k++) xT[(NFEAT+k)*PITCH+row] = EMBL[j*EMBD+k];
    } else {
      int col = tid-128;
      const float4* wp = (const float4*)(W + (size_t)(cbase+col)*K);
      #pragma unroll
      for (int k4=0;k4<K/4;k4++){
        float4 v = wp[k4];
        wT[(4*k4+0)*PITCH+col]=v.x; wT[(4*k4+1)*PITCH+col]=v.y;
        wT[(4*k4+2)*PITCH+col]=v.z; wT[(4*k4+3)*PITCH+col]=v.w;
      }
    }
  } else {
    constexpr int K4 = K/4;
    for (int i=tid; i<128*K4; i+=256){
      int row = i/K4, k4 = i%K4;
      int gr = rbase+row; if (gr >= NN) gr = NN-1;
      float4 v = ((const float4*)xin)[(size_t)gr*K4 + k4];
      xT[(4*k4+0)*PITCH+row]=v.x; xT[(4*k4+1)*PITCH+row]=v.y;
      xT[(4*k4+2)*PITCH+row]=v.z; xT[(4*k4+3)*PITCH+row]=v.w;
    }
    for (int i=tid; i<128*K4; i+=256){
      int col = i/K4, k4 = i%K4;
      float4 v = ((const float4*)W)[(size_t)(cbase+col)*K4 + k4];
      wT[(4*k4+0)*PITCH+col]=v.x; wT[(4*k4+1)*PITCH+col]=v.y;
      wT[(4*k4+2)*PITCH+col]=v.z; wT[(4*k4+3)*PITCH+col]=v.w;
    }
  }
  __syncthreads();
  int lane = tid & 63, w = tid >> 6;
  int r0 = (w>>1)*64 + (lane&7)*8;
  int c0 = (w&1)*64 + (lane>>3)*8;
  float acc[8][8];
  #pragma unroll
  for (int i=0;i<8;i++)
    #pragma unroll
    for (int j=0;j<8;j++) acc[i][j]=0.f;
  #pragma unroll 4
  for (int k=0;k<K;k++){
    float a[8], b[8];
    *(float4*)&a[0] = *(const float4*)&xT[k*PITCH + r0];
    *(float4*)&a[4] = *(const float4*)&xT[k*PITCH + r0 + 4];
    *(float4*)&b[0] = *(const float4*)&wT[k*PITCH + c0];
    *(float4*)&b[4] = *(const float4*)&wT[k*PITCH + c0 + 4];
    #pragma unroll
    for (int i=0;i<8;i++)
      #pragma unroll
      for (int j=0;j<8;j++) acc[i][j] += a[i]*b[j];
  }
  if (blockIdx.y==0 && tid < 128){
    int row = tid, gr = rbase+row;
    if (gr < NN){
      #pragma unroll
      for (int h=0;h<HH;h++){
        float a=0.f, b=0.f;
        for (int k=0;k<K;k++){
          float xv = xT[k*PITCH+row];
          a += xv*avp[h*K+k];
          b += xv*avp[HH*K+h*K+k];
        }
        si[(size_t)gr*HH+h]=a;
        sj[(size_t)gr*HH+h]=b;
      }
    }
  }
  #pragma unroll
  for (int i=0;i<8;i++){
    int n = rbase + r0 + i;
    if (n < NN){
      uint4 o;
      o.x = (unsigned)f2bf(acc[i][0]) | ((unsigned)f2bf(acc[i][1])<<16);
      o.y = (unsigned)f2bf(acc[i][2]) | ((unsigned)f2bf(acc[i][3])<<16);
      o.z = (unsigned)f2bf(acc[i][4]) | ((unsigned)f2bf(acc[i][5])<<16);
      o.w = (unsigned)f2bf(acc[i][6]) | ((unsigned)f2bf(acc[i][7])<<16);
      *(uint4*)(hout + (size_t)n*NCOL + cbase + c0) = o;
    }
  }
}

// ---------------- per-edge exp(lrelu(score)) + global per-head sum ----------
template<int HH>
__global__ void k_edge(const int* __restrict__ ei, const float* __restrict__ eattr,
                       const float* __restrict__ We, const float* __restrict__ si,
                       const float* __restrict__ sj, const int* __restrict__ epos,
                       float* __restrict__ pp, float* __restrict__ zred){
  int idx = blockIdx.x*blockDim.x + threadIdx.x;
  float z[HH];
  #pragma unroll
  for (int h=0;h<HH;h++) z[h]=0.f;
  if (idx < EE){
    int s = ei[idx], d = ei[EE+idx];
    const float4 ea = ((const float4*)eattr)[idx];
    int pos = epos[idx];
    if (HH==4){
      float4 siv = ((const float4*)si)[d];
      float4 sjv = ((const float4*)sj)[s];
      float te[4] = {siv.x+sjv.x, siv.y+sjv.y, siv.z+sjv.z, siv.w+sjv.w};
      float pv[4];
      #pragma unroll
      for (int h=0;h<4;h++){
        float t = te[h] + ea.x*We[h*EFEAT+0] + ea.y*We[h*EFEAT+1]
                        + ea.z*We[h*EFEAT+2] + ea.w*We[h*EFEAT+3];
        t = (t>0.f)? t : 0.2f*t;
        float p = expf(t);
        z[h]=p; pv[h]=p;
      }
      ((float4*)pp)[pos] = make_float4(pv[0],pv[1],pv[2],pv[3]);
    } else {
      float t = si[d] + sj[s]
              + ea.x*We[0] + ea.y*We[1] + ea.z*We[2] + ea.w*We[3];
      t = (t>0.f)? t : 0.2f*t;
      float p = expf(t);
      z[0]=p;
      pp[pos] = p;
    }
  } else if (idx < EEN){
    int n = idx-EE;
    int pos = n*STRIDE;
    if (HH==4){
      float4 siv = ((const float4*)si)[n];
      float4 sjv = ((const float4*)sj)[n];
      float te[4] = {siv.x+sjv.x, siv.y+sjv.y, siv.z+sjv.z, siv.w+sjv.w};
      float pv[4];
      #pragma unroll
      for (int h=0;h<4;h++){
        float t = te[h];
        t = (t>0.f)? t : 0.2f*t;
        float p = expf(t);
        z[h]=p; pv[h]=p;
      }
      ((float4*)pp)[pos] = make_float4(pv[0],pv[1],pv[2],pv[3]);
    } else {
      float t = si[n]+sj[n];
      t = (t>0.f)? t : 0.2f*t;
      float p = expf(t);
      z[0]=p;
      pp[pos]=p;
    }
  }
  __shared__ float zs[4][HH];
  #pragma unroll
  for (int h=0;h<HH;h++){
    float v=z[h];
    #pragma unroll
    for (int off=32; off>0; off>>=1) v += __shfl_xor(v,off,64);
    if ((threadIdx.x&63)==0) zs[threadIdx.x>>6][h]=v;
  }
  __syncthreads();
  if (threadIdx.x < HH){
    float tot = zs[0][threadIdx.x]+zs[1][threadIdx.x]
              + zs[2][threadIdx.x]+zs[3][threadIdx.x];
    atomicAdd(&zred[threadIdx.x], tot);
  }
}

// ---------------- pull aggregation: 1 wave = 2 nodes interleaved ----------
// 256-thr block = 4 waves = 8 nodes. Each wave walks TWO independent
// 8-unrolled CSR streams (16 h-gathers in flight, no barrier). Tail handled
// by clamp-to-self + multiply-by-0 predication (no pad storage -> no FETCH
// amplification; clamped slot's line is already L1-hot). col+pp stream, only
// h random-gathers (R10-proven invariant).
template<int HH,int CC,bool DO_ELU>
__global__ __launch_bounds__(256)
void k_agg(const unsigned short* __restrict__ hb, const float* __restrict__ pp,
           const float* __restrict__ zred, const int* __restrict__ fill,
           const int* __restrict__ col, float* __restrict__ outp){
  constexpr int HC = HH*CC;
  constexpr int V  = HC/64;
  using LT = typename ldt<V>::T;
  int wave = threadIdx.x>>6, lane = threadIdx.x&63;
  int n0 = blockIdx.x*8 + wave*2;        // NN % 8 == 0
  int n1 = n0 + 1;
  int hd = (lane*V)/CC;
  float acc0[V], acc1[V];
  #pragma unroll
  for (int v=0;v<V;v++){ acc0[v]=0.f; acc1[v]=0.f; }
  int beg0 = n0*STRIDE, cnt0 = 1 + fill[n0];
  int beg1 = n1*STRIDE, cnt1 = 1 + fill[n1];
  int cmax = (cnt0 > cnt1) ? cnt0 : cnt1;
  for (int it=0; it<cmax; it+=8){
    int idx0[8], idx1[8];
    #pragma unroll
    for (int k=0;k<8;k++){
      idx0[k] = (it+k < cnt0) ? beg0+it+k : beg0;   // clamp to self slot
      idx1[k] = (it+k < cnt1) ? beg1+it+k : beg1;
    }
    int sr0[8], sr1[8];
    #pragma unroll
    for (int k=0;k<8;k++){ sr0[k]=col[idx0[k]]; sr1[k]=col[idx1[k]]; }
    float p0[8], p1[8];
    #pragma unroll
    for (int k=0;k<8;k++){
      float t0 = (HH==4) ? pp[(size_t)idx0[k]*4+hd] : pp[idx0[k]];
      float t1 = (HH==4) ? pp[(size_t)idx1[k]*4+hd] : pp[idx1[k]];
      p0[k] = (it+k < cnt0) ? t0 : 0.f;
      p1[k] = (it+k < cnt1) ? t1 : 0.f;
    }
    LT h0[8], h1[8];
    #pragma unroll
    for (int k=0;k<8;k++){
      h0[k] = ((const LT*)(hb + (size_t)sr0[k]*HC))[lane];
      h1[k] = ((const LT*)(hb + (size_t)sr1[k]*HC))[lane];
    }
    #pragma unroll
    for (int k=0;k<8;k++){
      if constexpr (V==4){
        acc0[0] += p0[k]*bfl(h0[k].x); acc0[1] += p0[k]*bfh(h0[k].x);
        acc0[2] += p0[k]*bfl(h0[k].y); acc0[3] += p0[k]*bfh(h0[k].y);
        acc1[0] += p1[k]*bfl(h1[k].x); acc1[1] += p1[k]*bfh(h1[k].x);
        acc1[2] += p1[k]*bfl(h1[k].y); acc1[3] += p1[k]*bfh(h1[k].y);
      } else {
        acc0[0] += p0[k]*bfl(h0[k]);   acc0[1] += p0[k]*bfh(h0[k]);
        acc1[0] += p1[k]*bfl(h1[k]);   acc1[1] += p1[k]*bfh(h1[k]);
      }
    }
  }
  float invZ = 1.0f/zred[hd];
  #pragma unroll
  for (int v=0;v<V;v++){ acc0[v] *= invZ; acc1[v] *= invZ; }
  if (HH==4){
    #pragma unroll
    for (int off=16; off<64; off<<=1){
      #pragma unroll
      for (int v=0;v<V;v++){
        acc0[v] += __shfl_xor(acc0[v], off, 64);
        acc1[v] += __shfl_xor(acc1[v], off, 64);
      }
    }
    if (lane < 16){
      float4 o0, o1;
      o0.x=0.25f*acc0[0]; o0.y=0.25f*acc0[1]; o0.z=0.25f*acc0[2]; o0.w=0.25f*acc0[3];
      o1.x=0.25f*acc1[0]; o1.y=0.25f*acc1[1]; o1.z=0.25f*acc1[2]; o1.w=0.25f*acc1[3];
      if (DO_ELU){
        o0.x=(o0.x>0.f)?o0.x:expm1f(o0.x); o0.y=(o0.y>0.f)?o0.y:expm1f(o0.y);
        o0.z=(o0.z>0.f)?o0.z:expm1f(o0.z); o0.w=(o0.w>0.f)?o0.w:expm1f(o0.w);
        o1.x=(o1.x>0.f)?o1.x:expm1f(o1.x); o1.y=(o1.y>0.f)?o1.y:expm1f(o1.y);
        o1.z=(o1.z>0.f)?o1.z:expm1f(o1.z); o1.w=(o1.w>0.f)?o1.w:expm1f(o1.w);
      }
      ((float4*)outp)[(size_t)n0*(CC/4)+lane] = o0;
      ((float4*)outp)[(size_t)n1*(CC/4)+lane] = o1;
    }
  } else {
    float2 o0, o1;
    o0.x=acc0[0]; o0.y=acc0[1];
    o1.x=acc1[0]; o1.y=acc1[1];
    if (DO_ELU){
      o0.x=(o0.x>0.f)?o0.x:expm1f(o0.x); o0.y=(o0.y>0.f)?o0.y:expm1f(o0.y);
      o1.x=(o1.x>0.f)?o1.x:expm1f(o1.x); o1.y=(o1.y>0.f)?o1.y:expm1f(o1.y);
    }
    ((float2*)outp)[(size_t)n0*(CC/2)+lane] = o0;
    ((float2*)outp)[(size_t)n1*(CC/2)+lane] = o1;
  }
}

extern "C" void kernel_launch(void* const* d_in, const int* in_sizes, int n_in,
                              void* d_out, int out_size, void* d_ws, size_t ws_size,
                              hipStream_t stream){
  const float* x    = (const float*)d_in[0];
  const int*   ei   = (const int*)d_in[1];
  const float* eatt = (const float*)d_in[2];
  const int*   jt   = (const int*)d_in[3];
  const float* emb  = (const float*)d_in[4];
  const float* W0   = (const float*)d_in[5];
  const float* as0  = (const float*)d_in[6];
  const float* ad0  = (const float*)d_in[7];
  const float* We0  = (const float*)d_in[8];
  const float* W1   = (const float*)d_in[9];
  const float* as1  = (const float*)d_in[10];
  const float* ad1  = (const float*)d_in[11];
  const float* We1  = (const float*)d_in[12];
  const float* W2   = (const float*)d_in[13];
  const float* as2  = (const float*)d_in[14];
  const float* ad2  = (const float*)d_in[15];
  const float* We2  = (const float*)d_in[16];
  float* out = (float*)d_out;

  char* p = (char*)d_ws;
  auto alloc = [&](size_t bytes)->char*{
    char* r = p; p += (bytes + 255) & ~(size_t)255; return r;
  };
  unsigned short* hbuf = (unsigned short*)alloc((size_t)NN*256*2); // 25.6 MB bf16
  float* x1     = (float*)alloc((size_t)NN*64*4);
  float* x2     = (float*)alloc((size_t)NN*64*4);
  float* si     = (float*)alloc((size_t)NN*4*4);
  float* sj     = (float*)alloc((size_t)NN*4*4);
  float* pp     = (float*)alloc((size_t)NN*STRIDE*16); // 51.2 MB CSR-slot alphas
  int*   fill   = (int*)alloc((size_t)NN*4);
  int*   col    = (int*)alloc((size_t)NN*STRIDE*4);    // 12.8 MB fixed-stride CSR
  int*   epos   = (int*)alloc((size_t)EE*4);
  float* av0    = (float*)alloc(512*4);
  float* av1    = (float*)alloc(512*4);
  float* av2    = (float*)alloc(512*4);
  float* zred   = (float*)alloc(3*8*4);

  k_av3    <<<dim3((NN+255)/256),  256, 0, stream>>>(W0,as0,ad0,av0, W1,as1,ad1,av1,
                                                     W2,as2,ad2,av2, fill, zred);
  k_scatter<<<dim3((EEN+255)/256), 256, 0, stream>>>(ei, fill, col, epos);

  dim3 gg01((NN+127)/128, 2);
  dim3 gg2 ((NN+127)/128, 1);
  dim3 egrid((EEN+255)/256);
  dim3 agrid(NN/8);

  // layer 0: concat(x, emb[jt]) -> [N,4,64]
  k_gemm<IN0,256,4,true> <<<gg01, 256, 0, stream>>>(x, jt, emb, W0, av0, hbuf, si, sj);
  k_edge<4>              <<<egrid,256, 0, stream>>>(ei, eatt, We0, si, sj, epos, pp, zred+0);
  k_agg<4,64,true>       <<<agrid,256, 0, stream>>>(hbuf, pp, zred+0, fill, col, x1);

  // layer 1: 64 -> [N,4,64]
  k_gemm<64,256,4,false> <<<gg01, 256, 0, stream>>>(x1, jt, emb, W1, av1, hbuf, si, sj);
  k_edge<4>              <<<egrid,256, 0, stream>>>(ei, eatt, We1, si, sj, epos, pp, zred+8);
  k_agg<4,64,true>       <<<agrid,256, 0, stream>>>(hbuf, pp, zred+8, fill, col, x2);

  // layer 2: 64 -> [N,1,128], no ELU on final output
  k_gemm<64,128,1,false> <<<gg2,  256, 0, stream>>>(x2, jt, emb, W2, av2, hbuf, si, sj);
  k_edge<1>              <<<egrid,256, 0, stream>>>(ei, eatt, We2, si, sj, epos, pp, zred+16);
  k_agg<1,128,false>     <<<agrid,256, 0, stream>>>(hbuf, pp, zred+16, fill, col, out);
}

// Round 13
// 540.486 us; speedup vs baseline: 1.0362x; 1.0289x over previous
//
#include <hip/hip_runtime.h>
#include <math.h>

#define NN 50000
#define EE 800000
#define EEN (EE+NN)          // edges + self loops
#define STRIDE 64            // fixed CSR stride: self + up to 63 in-edges
#define NFEAT 4
#define EFEAT 4
#define EMBD 16
#define IN0 20   // NF + EMB
#define HIDD 64
#define OUTD 128

// bf16 helpers: storage = unsigned short, RTN-even pack, shift-decode
__device__ __forceinline__ unsigned short f2bf(float f){
  unsigned u = __float_as_uint(f);
  return (unsigned short)((u + 0x7FFFu + ((u>>16)&1u)) >> 16);
}
__device__ __forceinline__ float bfl(unsigned u){ return __uint_as_float(u<<16); }
__device__ __forceinline__ float bfh(unsigned u){ return __uint_as_float(u & 0xFFFF0000u); }

template<int V> struct ldt;
template<> struct ldt<4>{ using T = uint2; };
template<> struct ldt<2>{ using T = unsigned int; };

// ---------------- fixed-stride CSR scatter (one kernel, no scan) ----------
// col[n*64] = n (self); col[n*64+1+k] = src. epos[e] = CSR slot of edge e so
// k_edge writes alpha IN CSR ORDER (k_agg streams it — R6/R10-proven; random
// pp reads in k_agg cost +47MB FETCH, measured R7/R9).
__global__ void k_scatter(const int* __restrict__ ei, int* fill,
                          int* __restrict__ col, int* __restrict__ epos){
  int idx = blockIdx.x*blockDim.x + threadIdx.x;
  if (idx < EE){
    int d = ei[EE+idx];
    int pos = atomicAdd(&fill[d],1);
    col[d*STRIDE + 1 + pos] = ei[idx];
    epos[idx] = d*STRIDE + 1 + pos;
  } else if (idx < EEN){
    int n = idx-EE;
    col[n*STRIDE] = n;
  }
}

// ---------------- av (3 layers) + zred init + fill zero, one launch --------
template<int F_IN,int HH,int CC>
__device__ __forceinline__ void av_one(const float* W, const float* asrc,
                                       const float* adst, float* av, int tid){
  if (tid >= HH*F_IN) return;
  int h = tid / F_IN, f = tid % F_IN;
  float s1=0.f, s2=0.f;
  for (int c=0;c<CC;c++){
    float wv = W[(size_t)(h*CC+c)*F_IN+f];
    s1 += asrc[h*CC+c]*wv;
    s2 += adst[h*CC+c]*wv;
  }
  av[tid] = s1;
  av[HH*F_IN+tid] = s2;
}
__global__ void k_av3(const float* W0, const float* as0, const float* ad0, float* av0,
                      const float* W1, const float* as1, const float* ad1, float* av1,
                      const float* W2, const float* as2, const float* ad2, float* av2,
                      int* fill, float* zred){
  int tid = threadIdx.x;
  int gi = blockIdx.x*256 + tid;
  if (gi < NN) fill[gi] = 0;
  if      (blockIdx.x==0){ av_one<IN0,4,64> (W0, as0, ad0, av0, tid); if (tid<24) zred[tid]=0.f; }
  else if (blockIdx.x==1) av_one<64,4,64>  (W1, as1, ad1, av1, tid);
  else if (blockIdx.x==2) av_one<64,1,128> (W2, as2, ad2, av2, tid);
}

// ---------------- outer-product register-tiled GEMM + fused scores --------
template<int K,int NCOL,int HH,bool CONCAT>
__global__ __launch_bounds__(256)
void k_gemm(const float* __restrict__ xin, const int* __restrict__ jt,
            const float* __restrict__ emb, const float* __restrict__ W,
            const float* __restrict__ avp, unsigned short* __restrict__ hout,
            float* __restrict__ si, float* __restrict__ sj){
  constexpr int PITCH = 132;
  __shared__ float xT[K*PITCH];
  __shared__ float wT[K*PITCH];
  __shared__ float EMBL[CONCAT ? 17*EMBD : 1];
  int tid = threadIdx.x;
  int rbase = blockIdx.x*128, cbase = blockIdx.y*128;
  if (CONCAT){
    for (int i=tid; i<17*EMBD; i+=256) EMBL[i]=emb[i];
    __syncthreads();
    if (tid < 128){
      int row = tid;
      int gr = rbase+row; if (gr >= NN) gr = NN-1;
      float4 v = ((const float4*)xin)[gr];
      xT[0*PITCH+row]=v.x; xT[1*PITCH+row]=v.y;
      xT[2*PITCH+row]=v.z; xT[3*PITCH+row]=v.w;
      int j = jt[gr];
      #pragma unroll
      for (int k=0;k<EMBD;k++) xT[(NFEAT+k)*PITCH+row] = EMBL[j*EMBD+k];
    } else {
      int col = tid-128;
      const float4* wp = (const float4*)(W + (size_t)(cbase+col)*K);
      #pragma unroll
      for (int k4=0;k4<K/4;k4++){
        float4 v = wp[k4];
        wT[(4*k4+0)*PITCH+col]=v.x; wT[(4*k4+1)*PITCH+col]=v.y;
        wT[(4*k4+2)*PITCH+col]=v.z; wT[(4*k4+3)*PITCH+col]=v.w;
      }
    }
  } else {
    constexpr int K4 = K/4;
    for (int i=tid; i<128*K4; i+=256){
      int row = i/K4, k4 = i%K4;
      int gr = rbase+row; if (gr >= NN) gr = NN-1;
      float4 v = ((const float4*)xin)[(size_t)gr*K4 + k4];
      xT[(4*k4+0)*PITCH+row]=v.x; xT[(4*k4+1)*PITCH+row]=v.y;
      xT[(4*k4+2)*PITCH+row]=v.z; xT[(4*k4+3)*PITCH+row]=v.w;
    }
    for (int i=tid; i<128*K4; i+=256){
      int col = i/K4, k4 = i%K4;
      float4 v = ((const float4*)W)[(size_t)(cbase+col)*K4 + k4];
      wT[(4*k4+0)*PITCH+col]=v.x; wT[(4*k4+1)*PITCH+col]=v.y;
      wT[(4*k4+2)*PITCH+col]=v.z; wT[(4*k4+3)*PITCH+col]=v.w;
    }
  }
  __syncthreads();
  int lane = tid & 63, w = tid >> 6;
  int r0 = (w>>1)*64 + (lane&7)*8;
  int c0 = (w&1)*64 + (lane>>3)*8;
  float acc[8][8];
  #pragma unroll
  for (int i=0;i<8;i++)
    #pragma unroll
    for (int j=0;j<8;j++) acc[i][j]=0.f;
  #pragma unroll 4
  for (int k=0;k<K;k++){
    float a[8], b[8];
    *(float4*)&a[0] = *(const float4*)&xT[k*PITCH + r0];
    *(float4*)&a[4] = *(const float4*)&xT[k*PITCH + r0 + 4];
    *(float4*)&b[0] = *(const float4*)&wT[k*PITCH + c0];
    *(float4*)&b[4] = *(const float4*)&wT[k*PITCH + c0 + 4];
    #pragma unroll
    for (int i=0;i<8;i++)
      #pragma unroll
      for (int j=0;j<8;j++) acc[i][j] += a[i]*b[j];
  }
  if (blockIdx.y==0 && tid < 128){
    int row = tid, gr = rbase+row;
    if (gr < NN){
      #pragma unroll
      for (int h=0;h<HH;h++){
        float a=0.f, b=0.f;
        for (int k=0;k<K;k++){
          float xv = xT[k*PITCH+row];
          a += xv*avp[h*K+k];
          b += xv*avp[HH*K+h*K+k];
        }
        si[(size_t)gr*HH+h]=a;
        sj[(size_t)gr*HH+h]=b;
      }
    }
  }
  #pragma unroll
  for (int i=0;i<8;i++){
    int n = rbase + r0 + i;
    if (n < NN){
      uint4 o;
      o.x = (unsigned)f2bf(acc[i][0]) | ((unsigned)f2bf(acc[i][1])<<16);
      o.y = (unsigned)f2bf(acc[i][2]) | ((unsigned)f2bf(acc[i][3])<<16);
      o.z = (unsigned)f2bf(acc[i][4]) | ((unsigned)f2bf(acc[i][5])<<16);
      o.w = (unsigned)f2bf(acc[i][6]) | ((unsigned)f2bf(acc[i][7])<<16);
      *(uint4*)(hout + (size_t)n*NCOL + cbase + c0) = o;
    }
  }
}

// ---------------- per-edge exp(lrelu(score)) + global per-head sum ----------
template<int HH>
__global__ void k_edge(const int* __restrict__ ei, const float* __restrict__ eattr,
                       const float* __restrict__ We, const float* __restrict__ si,
                       const float* __restrict__ sj, const int* __restrict__ epos,
                       float* __restrict__ pp, float* __restrict__ zred){
  int idx = blockIdx.x*blockDim.x + threadIdx.x;
  float z[HH];
  #pragma unroll
  for (int h=0;h<HH;h++) z[h]=0.f;
  if (idx < EE){
    int s = ei[idx], d = ei[EE+idx];
    const float4 ea = ((const float4*)eattr)[idx];
    int pos = epos[idx];
    if (HH==4){
      float4 siv = ((const float4*)si)[d];
      float4 sjv = ((const float4*)sj)[s];
      float te[4] = {siv.x+sjv.x, siv.y+sjv.y, siv.z+sjv.z, siv.w+sjv.w};
      float pv[4];
      #pragma unroll
      for (int h=0;h<4;h++){
        float t = te[h] + ea.x*We[h*EFEAT+0] + ea.y*We[h*EFEAT+1]
                        + ea.z*We[h*EFEAT+2] + ea.w*We[h*EFEAT+3];
        t = (t>0.f)? t : 0.2f*t;
        float p = expf(t);
        z[h]=p; pv[h]=p;
      }
      ((float4*)pp)[pos] = make_float4(pv[0],pv[1],pv[2],pv[3]);
    } else {
      float t = si[d] + sj[s]
              + ea.x*We[0] + ea.y*We[1] + ea.z*We[2] + ea.w*We[3];
      t = (t>0.f)? t : 0.2f*t;
      float p = expf(t);
      z[0]=p;
      pp[pos] = p;
    }
  } else if (idx < EEN){
    int n = idx-EE;
    int pos = n*STRIDE;
    if (HH==4){
      float4 siv = ((const float4*)si)[n];
      float4 sjv = ((const float4*)sj)[n];
      float te[4] = {siv.x+sjv.x, siv.y+sjv.y, siv.z+sjv.z, siv.w+sjv.w};
      float pv[4];
      #pragma unroll
      for (int h=0;h<4;h++){
        float t = te[h];
        t = (t>0.f)? t : 0.2f*t;
        float p = expf(t);
        z[h]=p; pv[h]=p;
      }
      ((float4*)pp)[pos] = make_float4(pv[0],pv[1],pv[2],pv[3]);
    } else {
      float t = si[n]+sj[n];
      t = (t>0.f)? t : 0.2f*t;
      float p = expf(t);
      z[0]=p;
      pp[pos]=p;
    }
  }
  __shared__ float zs[4][HH];
  #pragma unroll
  for (int h=0;h<HH;h++){
    float v=z[h];
    #pragma unroll
    for (int off=32; off>0; off>>=1) v += __shfl_xor(v,off,64);
    if ((threadIdx.x&63)==0) zs[threadIdx.x>>6][h]=v;
  }
  __syncthreads();
  if (threadIdx.x < HH){
    float tot = zs[0][threadIdx.x]+zs[1][threadIdx.x]
              + zs[2][threadIdx.x]+zs[3][threadIdx.x];
    atomicAdd(&zred[threadIdx.x], tot);
  }
}

// ---------------- pull-mode aggregation, wave-per-node, bf16 gather --------
// R10-proven optimum: 1 wave per node, 8-edge unroll + serial remainder;
// col (4B) + pp (CSR-ordered, 16B) stream; only h random-gathers. Across six
// structural variants (R6-R12), dur tracked FETCH/3.4TB/s — this config sits
// on the FETCH floor (194MB ~= 8 XCDs x 25.6MB hbuf, per-XCD L2 re-fetch).
template<int HH,int CC,bool DO_ELU>
__global__ __launch_bounds__(256)
void k_agg(const unsigned short* __restrict__ hb, const float* __restrict__ pp,
           const float* __restrict__ zred, const int* __restrict__ fill,
           const int* __restrict__ col, float* __restrict__ outp){
  constexpr int HC = HH*CC;
  constexpr int V  = HC/64;
  using LT = typename ldt<V>::T;
  int wave = threadIdx.x>>6, lane = threadIdx.x&63;
  int n = blockIdx.x*4 + wave;           // NN % 4 == 0
  int hd = (lane*V)/CC;
  float invZ = 1.0f/zred[hd];
  float acc[V];
  #pragma unroll
  for (int v=0;v<V;v++) acc[v]=0.f;
  auto mac = [&](float p, LT h){
    if constexpr (V==4){
      acc[0] += p*bfl(h.x); acc[1] += p*bfh(h.x);
      acc[2] += p*bfl(h.y); acc[3] += p*bfh(h.y);
    } else {
      acc[0] += p*bfl(h);   acc[1] += p*bfh(h);
    }
  };
  int beg = n*STRIDE, end = beg + 1 + fill[n];
  int i = beg;
  for (; i+8<=end; i+=8){
    int sr[8]; float p[8]; LT h[8];
    #pragma unroll
    for (int k=0;k<8;k++) sr[k]=col[i+k];
    #pragma unroll
    for (int k=0;k<8;k++)
      p[k] = (HH==4) ? pp[(size_t)(i+k)*4+hd] : pp[i+k];
    #pragma unroll
    for (int k=0;k<8;k++) h[k]=((const LT*)(hb + (size_t)sr[k]*HC))[lane];
    #pragma unroll
    for (int k=0;k<8;k++) mac(p[k], h[k]);
  }
  for (; i<end; i++){
    int sr = col[i];
    float p = (HH==4) ? pp[(size_t)i*4+hd] : pp[i];
    LT h = ((const LT*)(hb + (size_t)sr*HC))[lane];
    mac(p, h);
  }
  #pragma unroll
  for (int v=0;v<V;v++) acc[v] *= invZ;
  if (HH==4){
    #pragma unroll
    for (int off=16; off<64; off<<=1){
      #pragma unroll
      for (int v=0;v<V;v++) acc[v] += __shfl_xor(acc[v], off, 64);
    }
    if (lane < 16){
      float4 o;
      o.x=0.25f*acc[0]; o.y=0.25f*acc[1]; o.z=0.25f*acc[2]; o.w=0.25f*acc[3];
      if (DO_ELU){
        o.x = (o.x>0.f)? o.x : expm1f(o.x);
        o.y = (o.y>0.f)? o.y : expm1f(o.y);
        o.z = (o.z>0.f)? o.z : expm1f(o.z);
        o.w = (o.w>0.f)? o.w : expm1f(o.w);
      }
      ((float4*)outp)[(size_t)n*(CC/4)+lane] = o;
    }
  } else {
    float2 o; o.x=acc[0]; o.y=acc[1];
    if (DO_ELU){
      o.x = (o.x>0.f)? o.x : expm1f(o.x);
      o.y = (o.y>0.f)? o.y : expm1f(o.y);
    }
    ((float2*)outp)[(size_t)n*(CC/2)+lane] = o;
  }
}

extern "C" void kernel_launch(void* const* d_in, const int* in_sizes, int n_in,
                              void* d_out, int out_size, void* d_ws, size_t ws_size,
                              hipStream_t stream){
  const float* x    = (const float*)d_in[0];
  const int*   ei   = (const int*)d_in[1];
  const float* eatt = (const float*)d_in[2];
  const int*   jt   = (const int*)d_in[3];
  const float* emb  = (const float*)d_in[4];
  const float* W0   = (const float*)d_in[5];
  const float* as0  = (const float*)d_in[6];
  const float* ad0  = (const float*)d_in[7];
  const float* We0  = (const float*)d_in[8];
  const float* W1   = (const float*)d_in[9];
  const float* as1  = (const float*)d_in[10];
  const float* ad1  = (const float*)d_in[11];
  const float* We1  = (const float*)d_in[12];
  const float* W2   = (const float*)d_in[13];
  const float* as2  = (const float*)d_in[14];
  const float* ad2  = (const float*)d_in[15];
  const float* We2  = (const float*)d_in[16];
  float* out = (float*)d_out;

  char* p = (char*)d_ws;
  auto alloc = [&](size_t bytes)->char*{
    char* r = p; p += (bytes + 255) & ~(size_t)255; return r;
  };
  unsigned short* hbuf = (unsigned short*)alloc((size_t)NN*256*2); // 25.6 MB bf16
  float* x1     = (float*)alloc((size_t)NN*64*4);
  float* x2     = (float*)alloc((size_t)NN*64*4);
  float* si     = (float*)alloc((size_t)NN*4*4);
  float* sj     = (float*)alloc((size_t)NN*4*4);
  float* pp     = (float*)alloc((size_t)NN*STRIDE*16); // 51.2 MB CSR-slot alphas
  int*   fill   = (int*)alloc((size_t)NN*4);
  int*   col    = (int*)alloc((size_t)NN*STRIDE*4);    // 12.8 MB fixed-stride CSR
  int*   epos   = (int*)alloc((size_t)EE*4);
  float* av0    = (float*)alloc(512*4);
  float* av1    = (float*)alloc(512*4);
  float* av2    = (float*)alloc(512*4);
  float* zred   = (float*)alloc(3*8*4);

  k_av3    <<<dim3((NN+255)/256),  256, 0, stream>>>(W0,as0,ad0,av0, W1,as1,ad1,av1,
                                                     W2,as2,ad2,av2, fill, zred);
  k_scatter<<<dim3((EEN+255)/256), 256, 0, stream>>>(ei, fill, col, epos);

  dim3 gg01((NN+127)/128, 2);
  dim3 gg2 ((NN+127)/128, 1);
  dim3 egrid((EEN+255)/256);
  dim3 agrid(NN/4);

  // layer 0: concat(x, emb[jt]) -> [N,4,64]
  k_gemm<IN0,256,4,true> <<<gg01, 256, 0, stream>>>(x, jt, emb, W0, av0, hbuf, si, sj);
  k_edge<4>              <<<egrid,256, 0, stream>>>(ei, eatt, We0, si, sj, epos, pp, zred+0);
  k_agg<4,64,true>       <<<agrid,256, 0, stream>>>(hbuf, pp, zred+0, fill, col, x1);

  // layer 1: 64 -> [N,4,64]
  k_gemm<64,256,4,false> <<<gg01, 256, 0, stream>>>(x1, jt, emb, W1, av1, hbuf, si, sj);
  k_edge<4>              <<<egrid,256, 0, stream>>>(ei, eatt, We1, si, sj, epos, pp, zred+8);
  k_agg<4,64,true>       <<<agrid,256, 0, stream>>>(hbuf, pp, zred+8, fill, col, x2);

  // layer 2: 64 -> [N,1,128], no ELU on final output
  k_gemm<64,128,1,false> <<<gg2,  256, 0, stream>>>(x2, jt, emb, W2, av2, hbuf, si, sj);
  k_edge<1>              <<<egrid,256, 0, stream>>>(ei, eatt, We2, si, sj, epos, pp, zred+16);
  k_agg<1,128,false>     <<<agrid,256, 0, stream>>>(hbuf, pp, zred+16, fill, col, out);
}